// Round 4
// baseline (948.323 us; speedup 1.0000x reference)
//
#include <hip/hip_runtime.h>
#include <hip/hip_bf16.h>

#define NN 100000
#define NE 1600000
#define NB 391        // ceil(NN/256) for node-per-thread kernels
#define NBUK 782      // ceil(NN/128): dst buckets of 128 nodes
#define NBLK 400      // edge partition blocks
#define CHUNK 4000    // edges per partition block (400*4000 = NE)

typedef unsigned short ushort_t;

static __device__ __forceinline__ float bf2f(ushort_t u) {
    union { unsigned int i; float f; } c; c.i = ((unsigned int)u) << 16; return c.f;
}
static __device__ __forceinline__ ushort_t f2bf(float f) {
    union { __hip_bfloat16 b; ushort_t u; } c; c.b = __float2bfloat16(f); return c.u;
}

// ---- per-block bucket histogram (LDS-privatized, no global atomics) ----
__global__ __launch_bounds__(256) void k_part_hist(const int* __restrict__ dst,
                                                   int* __restrict__ bhist) {
    __shared__ int h[NBUK];
    int t = threadIdx.x, b = blockIdx.x;
    for (int i = t; i < NBUK; i += 256) h[i] = 0;
    __syncthreads();
    int e0 = b * CHUNK;
    for (int r = 0; r < CHUNK; r += 256)
        if (r + t < CHUNK) atomicAdd(&h[dst[e0 + r + t] >> 7], 1);
    __syncthreads();
    for (int i = t; i < NBUK; i += 256) bhist[b * NBUK + i] = h[i];
}

// ---- per-bucket scan across blocks: base_excl[blk][bucket], coltot[bucket] ----
__global__ __launch_bounds__(512) void k_colscan(const int* __restrict__ bhist,
                                                 int* __restrict__ base_excl,
                                                 int* __restrict__ coltot) {
    __shared__ int s[512];
    int k = blockIdx.x, t = threadIdx.x;
    int v = (t < NBLK) ? bhist[t * NBUK + k] : 0;
    s[t] = v;
    __syncthreads();
#pragma unroll
    for (int o = 1; o < 512; o <<= 1) {
        int x = (t >= o) ? s[t - o] : 0;
        __syncthreads();
        s[t] += x;
        __syncthreads();
    }
    if (t < NBLK) base_excl[t * NBUK + k] = s[t] - v;
    if (t == 511) coltot[k] = s[511];
}

// ---- exclusive scan of bucket totals -> bstart, bcnt ----
__global__ __launch_bounds__(1024) void k_scanb2(const int* __restrict__ coltot,
                                                 int* __restrict__ bstart,
                                                 int* __restrict__ bcnt) {
    __shared__ int s[1024];
    int t = threadIdx.x;
    int v = (t < NBUK) ? coltot[t] : 0;
    s[t] = v;
    __syncthreads();
#pragma unroll
    for (int o = 1; o < 1024; o <<= 1) {
        int x = (t >= o) ? s[t - o] : 0;
        __syncthreads();
        s[t] += x;
        __syncthreads();
    }
    if (t < NBUK) { bstart[t] = s[t] - v; bcnt[t] = v; }
}

// ---- deterministic partition: ebuf[pos] = src | (dst&127)<<17 ----
__global__ __launch_bounds__(256) void k_scatter2(const int* __restrict__ ei,
                                                  const int* __restrict__ bstart,
                                                  const int* __restrict__ base_excl,
                                                  unsigned* __restrict__ ebuf) {
    __shared__ int cur[NBUK];
    int t = threadIdx.x, b = blockIdx.x;
    for (int i = t; i < NBUK; i += 256) cur[i] = 0;
    __syncthreads();
    int e0 = b * CHUNK;
    for (int r = 0; r < CHUNK; r += 256) {
        if (r + t < CHUNK) {
            int e = e0 + r + t;
            int sv = ei[e];
            int dv = ei[NE + e];
            int k = dv >> 7;
            int rk = atomicAdd(&cur[k], 1);   // LDS atomic
            int pos = bstart[k] + base_excl[b * NBUK + k] + rk;
            ebuf[pos] = (unsigned)sv | ((unsigned)(dv & 127) << 17);
        }
    }
}

// ---- per-bucket degree -> dinv (sequential reads, LDS counts) ----
__global__ __launch_bounds__(256) void k_degb(const int* __restrict__ bstart,
                                              const int* __restrict__ bcnt,
                                              const unsigned* __restrict__ ebuf,
                                              float* __restrict__ dinv) {
    __shared__ int cnt[128];
    int t = threadIdx.x, b = blockIdx.x;
    if (t < 128) cnt[t] = 0;
    __syncthreads();
    int base = bstart[b], ne = bcnt[b];
    for (int i = t; i < ne; i += 256) atomicAdd(&cnt[ebuf[base + i] >> 17], 1);
    __syncthreads();
    if (t < 128) {
        int node = b * 128 + t;
        if (node < NN) dinv[node] = rsqrtf((float)(cnt[t] + 1));
    }
}

// ---- h' = dinv[node] * (x @ W_conv), stored bf16 ----
__global__ __launch_bounds__(256) void k_gemm1(const float* __restrict__ x,
                                               const float* __restrict__ Wf,
                                               const float* __restrict__ dinv,
                                               ushort_t* __restrict__ hp) {
    int node = blockIdx.x * 256 + threadIdx.x;
    int nclamp = node < NN ? node : NN - 1;
    const float4* xr = (const float4*)(x + (size_t)nclamp * 128);
    float acc[64];
#pragma unroll
    for (int d = 0; d < 64; ++d) acc[d] = 0.f;

#pragma unroll 1
    for (int k0 = 0; k0 < 128; k0 += 8) {
        float4 u0 = xr[(k0 >> 2) + 0];
        float4 u1 = xr[(k0 >> 2) + 1];
        float xv[8] = {u0.x, u0.y, u0.z, u0.w, u1.x, u1.y, u1.z, u1.w};
#pragma unroll
        for (int kk = 0; kk < 8; ++kk) {
            const float* wrow = Wf + (k0 + kk) * 64;   // uniform address
#pragma unroll
            for (int d = 0; d < 64; ++d) acc[d] = fmaf(xv[kk], wrow[d], acc[d]);
        }
    }
    if (node < NN) {
        float di = dinv[node];
        uint4* hr = (uint4*)(hp + (size_t)node * 64);
#pragma unroll
        for (int d0 = 0; d0 < 64; d0 += 8) {
            uint4 o;
            o.x = (unsigned)f2bf(di * acc[d0 + 0]) | ((unsigned)f2bf(di * acc[d0 + 1]) << 16);
            o.y = (unsigned)f2bf(di * acc[d0 + 2]) | ((unsigned)f2bf(di * acc[d0 + 3]) << 16);
            o.z = (unsigned)f2bf(di * acc[d0 + 4]) | ((unsigned)f2bf(di * acc[d0 + 5]) << 16);
            o.w = (unsigned)f2bf(di * acc[d0 + 6]) | ((unsigned)f2bf(di * acc[d0 + 7]) << 16);
            hr[d0 >> 3] = o;
        }
    }
}

// ---- bucket aggregation in LDS: one block per 128-node bucket ----
// a[n,d] = relu( dinv[n] * (sum_{src->n} hp[src,d] + hp[n,d]) + b_conv[d] )
__global__ __launch_bounds__(256) void k_agg(const int* __restrict__ bstart,
                                             const int* __restrict__ bcnt,
                                             const unsigned* __restrict__ ebuf,
                                             const float* __restrict__ dinv,
                                             const ushort_t* __restrict__ hp,
                                             const float* __restrict__ b_conv,
                                             float* __restrict__ a) {
    __shared__ float agg[128 * 64];
    int t = threadIdx.x, b = blockIdx.x;
    for (int i = t; i < 128 * 64; i += 256) agg[i] = 0.f;
    __syncthreads();

    int base = bstart[b], ne = bcnt[b];
    int half = t >> 5, l = t & 31;                 // 8 half-waves x 32 lanes
    const unsigned* hpu = (const unsigned*)hp;     // 2 bf16 per uint

#pragma unroll 1
    for (int i0 = half * 8; i0 < ne; i0 += 64) {
        int rem = ne - i0;
        int m = rem < 8 ? rem : 8;                 // uniform per half-wave
        unsigned pe = 0;
        if (l < m) pe = ebuf[base + i0 + l];
        unsigned pp[8], vv[8];
#pragma unroll
        for (int u = 0; u < 8; ++u) {
            pp[u] = __shfl(pe, u, 32);
            if (u < m) vv[u] = hpu[(size_t)(pp[u] & 0x1FFFF) * 32 + l];
        }
#pragma unroll
        for (int u = 0; u < 8; ++u) {
            if (u < m) {
                int dl = pp[u] >> 17;
                atomicAdd(&agg[dl * 64 + 2 * l],     bf2f((ushort_t)(vv[u] & 0xFFFF)));
                atomicAdd(&agg[dl * 64 + 2 * l + 1], bf2f((ushort_t)(vv[u] >> 16)));
            }
        }
    }
    __syncthreads();

    int d = t & 63, w = t >> 6;                    // 4 waves write 32 nodes each
#pragma unroll 1
    for (int i = 0; i < 32; ++i) {
        int nl = w * 32 + i;
        int node = b * 128 + nl;
        if (node < NN) {
            float s = agg[nl * 64 + d];
            s += bf2f(hp[(size_t)node * 64 + d]);  // self-loop
            float v = dinv[node] * s + b_conv[d];
            a[(size_t)node * 64 + d] = fmaxf(v, 0.f);
        }
    }
}

// ---- epilogue GEMM: out = a @ W_lin + b_lin ----
__global__ __launch_bounds__(256) void k_epi(const float* __restrict__ a,
                                             const float* __restrict__ W2f,
                                             const float* __restrict__ b_lin,
                                             float* __restrict__ out) {
    int node = (blockIdx.x >> 1) * 256 + threadIdx.x;
    int half = blockIdx.x & 1;                 // uniform
    int nclamp = node < NN ? node : NN - 1;
    const float* ar = a + (size_t)nclamp * 64;

    float acc[64];
#pragma unroll
    for (int j = 0; j < 64; ++j) acc[j] = b_lin[half * 64 + j];  // uniform

#pragma unroll 1
    for (int k0 = 0; k0 < 64; k0 += 8) {
        float4 a0 = *(const float4*)(ar + k0);
        float4 a1 = *(const float4*)(ar + k0 + 4);
        float tt[8] = {a0.x, a0.y, a0.z, a0.w, a1.x, a1.y, a1.z, a1.w};
#pragma unroll
        for (int kk = 0; kk < 8; ++kk) {
            const float* wrow = W2f + (k0 + kk) * 128 + half * 64;   // uniform
#pragma unroll
            for (int j = 0; j < 64; ++j) acc[j] = fmaf(tt[kk], wrow[j], acc[j]);
        }
    }

    if (node < NN) {
        float4* orow = (float4*)(out + (size_t)node * 128 + half * 64);
#pragma unroll
        for (int j0 = 0; j0 < 64; j0 += 4) {
            float4 o; o.x = acc[j0]; o.y = acc[j0 + 1]; o.z = acc[j0 + 2]; o.w = acc[j0 + 3];
            orow[j0 >> 2] = o;
        }
    }
}

extern "C" void kernel_launch(void* const* d_in, const int* in_sizes, int n_in,
                              void* d_out, int out_size, void* d_ws, size_t ws_size,
                              hipStream_t stream) {
    const float* x  = (const float*)d_in[0];
    const int*   ei = (const int*)d_in[1];
    const float* Wc = (const float*)d_in[2];
    const float* bc = (const float*)d_in[3];
    const float* Wl = (const float*)d_in[4];
    const float* bl = (const float*)d_in[5];
    float* out = (float*)d_out;

    char* ws = (char*)d_ws;
    // layout (16B aligned), total ~47.7 MB; every byte written before read -> no memset
    int*      bhist     = (int*)(ws + 0);          // 400*782*4 = 1251200
    int*      base_excl = (int*)(ws + 1251200);    // 1251200
    int*      coltot    = (int*)(ws + 2502400);    // 3200
    int*      bstart    = (int*)(ws + 2505600);    // 3200
    int*      bcnt      = (int*)(ws + 2508800);    // 3200
    float*    dinv      = (float*)(ws + 2512000);  // 400384
    unsigned* ebuf      = (unsigned*)(ws + 2912384);   // 6400000
    ushort_t* hp        = (ushort_t*)(ws + 9312384);   // 12800000 (bf16)
    float*    a         = (float*)(ws + 22112384);     // 25600000

    k_part_hist<<<NBLK, 256, 0, stream>>>(ei + NE, bhist);
    k_colscan <<<NBUK, 512, 0, stream>>>(bhist, base_excl, coltot);
    k_scanb2  <<<1, 1024, 0, stream>>>(coltot, bstart, bcnt);
    k_scatter2<<<NBLK, 256, 0, stream>>>(ei, bstart, base_excl, ebuf);
    k_degb    <<<NBUK, 256, 0, stream>>>(bstart, bcnt, ebuf, dinv);
    k_gemm1   <<<NB, 256, 0, stream>>>(x, Wc, dinv, hp);
    k_agg     <<<NBUK, 256, 0, stream>>>(bstart, bcnt, ebuf, dinv, hp, bc, a);
    k_epi     <<<2 * NB, 256, 0, stream>>>(a, Wl, bl, out);
}

// Round 5
// 305.601 us; speedup vs baseline: 3.1031x; 3.1031x over previous
//
#include <hip/hip_runtime.h>
#include <hip/hip_bf16.h>

#define NN 100000
#define NE 1600000
#define NB 391        // ceil(NN/256)
#define NBUK 782      // ceil(NN/128): dst buckets of 128 nodes
#define NBLK 400      // edge partition blocks
#define CHUNK 4000    // edges per partition block (400*4000 = NE)

typedef unsigned short ushort_t;

static __device__ __forceinline__ float bf2f(ushort_t u) {
    union { unsigned int i; float f; } c; c.i = ((unsigned int)u) << 16; return c.f;
}
static __device__ __forceinline__ ushort_t f2bf(float f) {
    union { __hip_bfloat16 b; ushort_t u; } c; c.b = __float2bfloat16(f); return c.u;
}

// ---- per-block bucket histogram (LDS int atomics only) ----
__global__ __launch_bounds__(256) void k_part_hist(const int* __restrict__ dst,
                                                   int* __restrict__ bhist) {
    __shared__ int h[NBUK];
    int t = threadIdx.x, b = blockIdx.x;
    for (int i = t; i < NBUK; i += 256) h[i] = 0;
    __syncthreads();
    int e0 = b * CHUNK;
    for (int r = 0; r < CHUNK; r += 256)
        if (r + t < CHUNK) atomicAdd(&h[dst[e0 + r + t] >> 7], 1);
    __syncthreads();
    for (int i = t; i < NBUK; i += 256) bhist[b * NBUK + i] = h[i];
}

// ---- per-bucket scan across blocks ----
__global__ __launch_bounds__(512) void k_colscan(const int* __restrict__ bhist,
                                                 int* __restrict__ base_excl,
                                                 int* __restrict__ coltot) {
    __shared__ int s[512];
    int k = blockIdx.x, t = threadIdx.x;
    int v = (t < NBLK) ? bhist[t * NBUK + k] : 0;
    s[t] = v;
    __syncthreads();
#pragma unroll
    for (int o = 1; o < 512; o <<= 1) {
        int x = (t >= o) ? s[t - o] : 0;
        __syncthreads();
        s[t] += x;
        __syncthreads();
    }
    if (t < NBLK) base_excl[t * NBUK + k] = s[t] - v;
    if (t == 511) coltot[k] = s[511];
}

// ---- exclusive scan of bucket totals ----
__global__ __launch_bounds__(1024) void k_scanb2(const int* __restrict__ coltot,
                                                 int* __restrict__ bstart,
                                                 int* __restrict__ bcnt) {
    __shared__ int s[1024];
    int t = threadIdx.x;
    int v = (t < NBUK) ? coltot[t] : 0;
    s[t] = v;
    __syncthreads();
#pragma unroll
    for (int o = 1; o < 1024; o <<= 1) {
        int x = (t >= o) ? s[t - o] : 0;
        __syncthreads();
        s[t] += x;
        __syncthreads();
    }
    if (t < NBUK) { bstart[t] = s[t] - v; bcnt[t] = v; }
}

// ---- deterministic partition: ebuf[pos] = src | (dst&127)<<17 ----
__global__ __launch_bounds__(256) void k_scatter2(const int* __restrict__ ei,
                                                  const int* __restrict__ bstart,
                                                  const int* __restrict__ base_excl,
                                                  unsigned* __restrict__ ebuf) {
    __shared__ int cur[NBUK];
    int t = threadIdx.x, b = blockIdx.x;
    for (int i = t; i < NBUK; i += 256) cur[i] = 0;
    __syncthreads();
    int e0 = b * CHUNK;
    for (int r = 0; r < CHUNK; r += 256) {
        if (r + t < CHUNK) {
            int e = e0 + r + t;
            int sv = ei[e];
            int dv = ei[NE + e];
            int k = dv >> 7;
            int rk = atomicAdd(&cur[k], 1);   // LDS int atomic
            int pos = bstart[k] + base_excl[b * NBUK + k] + rk;
            ebuf[pos] = (unsigned)sv | ((unsigned)(dv & 127) << 17);
        }
    }
}

// ---- per-bucket counting sort -> dst-sorted csr, offsets/deg/dinv ----
__global__ __launch_bounds__(256) void k_sort(const int* __restrict__ bstart,
                                              const int* __restrict__ bcnt,
                                              const unsigned* __restrict__ ebuf,
                                              int* __restrict__ csr,
                                              int* __restrict__ offsets,
                                              int* __restrict__ deg,
                                              float* __restrict__ dinv) {
    __shared__ int hist[128];
    __shared__ int off[128];
    __shared__ int cur[128];
    int t = threadIdx.x, b = blockIdx.x;
    if (t < 128) hist[t] = 0;
    __syncthreads();
    int base = bstart[b], ne = bcnt[b];
    for (int i = t; i < ne; i += 256) atomicAdd(&hist[ebuf[base + i] >> 17], 1);
    __syncthreads();
    if (t < 128) off[t] = hist[t];
    __syncthreads();
#pragma unroll
    for (int o = 1; o < 128; o <<= 1) {
        int x = 0;
        if (t < 128 && t >= o) x = off[t - o];
        __syncthreads();
        if (t < 128) off[t] += x;
        __syncthreads();
    }
    if (t < 128) {
        int excl = off[t] - hist[t];
        cur[t] = excl;
        int node = b * 128 + t;
        if (node < NN) {
            offsets[node] = base + excl;   // absolute csr index
            deg[node]     = hist[t];
            dinv[node]    = rsqrtf((float)(hist[t] + 1));
        }
    }
    __syncthreads();
    for (int i = t; i < ne; i += 256) {
        unsigned pe = ebuf[base + i];
        int dl = pe >> 17;
        int pos = atomicAdd(&cur[dl], 1);  // LDS int atomic
        csr[base + pos] = (int)(pe & 0x1FFFF);
    }
}

// ---- h' = dinv[node] * (x @ W_conv), stored bf16 ----
__global__ __launch_bounds__(256) void k_gemm1(const float* __restrict__ x,
                                               const float* __restrict__ Wf,
                                               const float* __restrict__ dinv,
                                               ushort_t* __restrict__ hp) {
    int node = blockIdx.x * 256 + threadIdx.x;
    int nclamp = node < NN ? node : NN - 1;
    const float4* xr = (const float4*)(x + (size_t)nclamp * 128);
    float acc[64];
#pragma unroll
    for (int d = 0; d < 64; ++d) acc[d] = 0.f;

#pragma unroll 1
    for (int k0 = 0; k0 < 128; k0 += 8) {
        float4 u0 = xr[(k0 >> 2) + 0];
        float4 u1 = xr[(k0 >> 2) + 1];
        float xv[8] = {u0.x, u0.y, u0.z, u0.w, u1.x, u1.y, u1.z, u1.w};
#pragma unroll
        for (int kk = 0; kk < 8; ++kk) {
            const float* wrow = Wf + (k0 + kk) * 64;   // uniform address
#pragma unroll
            for (int d = 0; d < 64; ++d) acc[d] = fmaf(xv[kk], wrow[d], acc[d]);
        }
    }
    if (node < NN) {
        float di = dinv[node];
        uint4* hr = (uint4*)(hp + (size_t)node * 64);
#pragma unroll
        for (int d0 = 0; d0 < 64; d0 += 8) {
            uint4 o;
            o.x = (unsigned)f2bf(di * acc[d0 + 0]) | ((unsigned)f2bf(di * acc[d0 + 1]) << 16);
            o.y = (unsigned)f2bf(di * acc[d0 + 2]) | ((unsigned)f2bf(di * acc[d0 + 3]) << 16);
            o.z = (unsigned)f2bf(di * acc[d0 + 4]) | ((unsigned)f2bf(di * acc[d0 + 5]) << 16);
            o.w = (unsigned)f2bf(di * acc[d0 + 6]) | ((unsigned)f2bf(di * acc[d0 + 7]) << 16);
            hr[d0 >> 3] = o;
        }
    }
}

// ---- gather-side aggregation: one wave per node, register accumulation ----
// a[n,d] = relu( dinv[n] * (sum_{src in in(n)} hp[src,d] + hp[n,d]) + b_conv[d] ), bf16
__global__ __launch_bounds__(256) void k_gather(const int* __restrict__ offsets,
                                                const int* __restrict__ deg,
                                                const int* __restrict__ csr,
                                                const float* __restrict__ dinv,
                                                const ushort_t* __restrict__ hp,
                                                const float* __restrict__ b_conv,
                                                ushort_t* __restrict__ a) {
    int node = (blockIdx.x * 256 + threadIdx.x) >> 6;   // grid exactly NN waves
    int lane = threadIdx.x & 63;
    int start = offsets[node];
    int cnt   = deg[node];

    float s0 = 0.f, s1 = 0.f, s2 = 0.f, s3 = 0.f;
#pragma unroll 1
    for (int j0 = 0; j0 < cnt; j0 += 64) {
        int m = cnt - j0; m = m < 64 ? m : 64;   // wave-uniform
        int col = 0;
        if (lane < m) col = csr[start + j0 + lane];
        int jj = 0;
#pragma unroll 1
        for (; jj + 8 <= m; jj += 8) {
            int c[8];
#pragma unroll
            for (int u = 0; u < 8; ++u) c[u] = __shfl(col, jj + u, 64);
            float v[8];
#pragma unroll
            for (int u = 0; u < 8; ++u) v[u] = bf2f(hp[(size_t)c[u] * 64 + lane]);
            s0 += v[0] + v[4]; s1 += v[1] + v[5]; s2 += v[2] + v[6]; s3 += v[3] + v[7];
        }
        for (; jj < m; ++jj) {
            int c = __shfl(col, jj, 64);
            s0 += bf2f(hp[(size_t)c * 64 + lane]);
        }
    }
    float acc = (s0 + s1) + (s2 + s3);
    acc += bf2f(hp[(size_t)node * 64 + lane]);          // self-loop
    float v = dinv[node] * acc + b_conv[lane];
    a[(size_t)node * 64 + lane] = f2bf(fmaxf(v, 0.f));
}

// ---- epilogue GEMM: out = a @ W_lin + b_lin (a is bf16) ----
__global__ __launch_bounds__(256) void k_epi(const ushort_t* __restrict__ a,
                                             const float* __restrict__ W2f,
                                             const float* __restrict__ b_lin,
                                             float* __restrict__ out) {
    int node = (blockIdx.x >> 1) * 256 + threadIdx.x;
    int half = blockIdx.x & 1;                 // uniform
    int nclamp = node < NN ? node : NN - 1;
    const uint4* ar = (const uint4*)(a + (size_t)nclamp * 64);

    float acc[64];
#pragma unroll
    for (int j = 0; j < 64; ++j) acc[j] = b_lin[half * 64 + j];  // uniform

#pragma unroll 1
    for (int k0 = 0; k0 < 64; k0 += 8) {
        uint4 u = ar[k0 >> 3];
        float tt[8];
        tt[0] = __uint_as_float(u.x << 16); tt[1] = __uint_as_float(u.x & 0xffff0000u);
        tt[2] = __uint_as_float(u.y << 16); tt[3] = __uint_as_float(u.y & 0xffff0000u);
        tt[4] = __uint_as_float(u.z << 16); tt[5] = __uint_as_float(u.z & 0xffff0000u);
        tt[6] = __uint_as_float(u.w << 16); tt[7] = __uint_as_float(u.w & 0xffff0000u);
#pragma unroll
        for (int kk = 0; kk < 8; ++kk) {
            const float* wrow = W2f + (k0 + kk) * 128 + half * 64;   // uniform
#pragma unroll
            for (int j = 0; j < 64; ++j) acc[j] = fmaf(tt[kk], wrow[j], acc[j]);
        }
    }

    if (node < NN) {
        float4* orow = (float4*)(out + (size_t)node * 128 + half * 64);
#pragma unroll
        for (int j0 = 0; j0 < 64; j0 += 4) {
            float4 o; o.x = acc[j0]; o.y = acc[j0 + 1]; o.z = acc[j0 + 2]; o.w = acc[j0 + 3];
            orow[j0 >> 2] = o;
        }
    }
}

extern "C" void kernel_launch(void* const* d_in, const int* in_sizes, int n_in,
                              void* d_out, int out_size, void* d_ws, size_t ws_size,
                              hipStream_t stream) {
    const float* x  = (const float*)d_in[0];
    const int*   ei = (const int*)d_in[1];
    const float* Wc = (const float*)d_in[2];
    const float* bc = (const float*)d_in[3];
    const float* Wl = (const float*)d_in[4];
    const float* bl = (const float*)d_in[5];
    float* out = (float*)d_out;

    char* ws = (char*)d_ws;
    // total 42.1 MB; every byte written before read -> no memset needed
    int*      bhist     = (int*)(ws + 0);              // 1251200
    int*      base_excl = (int*)(ws + 1251200);        // 1251200
    int*      coltot    = (int*)(ws + 2502400);        // 3200
    int*      bstart    = (int*)(ws + 2505600);        // 3200
    int*      bcnt      = (int*)(ws + 2508800);        // 3200
    int*      offsets   = (int*)(ws + 2512000);        // 400384
    int*      deg       = (int*)(ws + 2912384);        // 400384
    float*    dinv      = (float*)(ws + 3312768);      // 400384
    unsigned* ebuf      = (unsigned*)(ws + 3713152);   // 6400000
    int*      csr       = (int*)(ws + 10113152);       // 6400000
    ushort_t* hp        = (ushort_t*)(ws + 16513152);  // 12800000 (bf16)
    ushort_t* a         = (ushort_t*)(ws + 29313152);  // 12800000 (bf16)

    k_part_hist<<<NBLK, 256, 0, stream>>>(ei + NE, bhist);
    k_colscan <<<NBUK, 512, 0, stream>>>(bhist, base_excl, coltot);
    k_scanb2  <<<1, 1024, 0, stream>>>(coltot, bstart, bcnt);
    k_scatter2<<<NBLK, 256, 0, stream>>>(ei, bstart, base_excl, ebuf);
    k_sort    <<<NBUK, 256, 0, stream>>>(bstart, bcnt, ebuf, csr, offsets, deg, dinv);
    k_gemm1   <<<NB, 256, 0, stream>>>(x, Wc, dinv, hp);
    k_gather  <<<NN * 64 / 256, 256, 0, stream>>>(offsets, deg, csr, dinv, hp, bc, a);
    k_epi     <<<2 * NB, 256, 0, stream>>>(a, Wl, bl, out);
}

// Round 6
// 251.759 us; speedup vs baseline: 3.7668x; 1.2139x over previous
//
#include <hip/hip_runtime.h>
#include <hip/hip_bf16.h>

#define NN 100000
#define NE 1600000
#define NBUK 782      // ceil(NN/128): dst buckets of 128 nodes
#define NBLK 400      // edge partition blocks
#define CHUNK 4000    // edges per partition block (400*4000 = NE)
#define NGB 1563      // ceil(NN/64): blocks for MFMA GEMMs

typedef unsigned short ushort_t;
typedef __bf16 bf16x8 __attribute__((ext_vector_type(8)));
typedef float  f32x4  __attribute__((ext_vector_type(4)));

static __device__ __forceinline__ float bf2f(ushort_t u) {
    union { unsigned int i; float f; } c; c.i = ((unsigned int)u) << 16; return c.f;
}
static __device__ __forceinline__ ushort_t f2bf(float f) {
    union { __hip_bfloat16 b; ushort_t u; } c; c.b = __float2bfloat16(f); return c.u;
}

// ---- per-block bucket histogram (LDS int atomics only) ----
__global__ __launch_bounds__(256) void k_part_hist(const int* __restrict__ dst,
                                                   int* __restrict__ bhist) {
    __shared__ int h[NBUK];
    int t = threadIdx.x, b = blockIdx.x;
    for (int i = t; i < NBUK; i += 256) h[i] = 0;
    __syncthreads();
    int e0 = b * CHUNK;
    for (int r = 0; r < CHUNK; r += 256)
        if (r + t < CHUNK) atomicAdd(&h[dst[e0 + r + t] >> 7], 1);
    __syncthreads();
    for (int i = t; i < NBUK; i += 256) bhist[b * NBUK + i] = h[i];
}

// ---- per-bucket scan across blocks ----
__global__ __launch_bounds__(512) void k_colscan(const int* __restrict__ bhist,
                                                 int* __restrict__ base_excl,
                                                 int* __restrict__ coltot) {
    __shared__ int s[512];
    int k = blockIdx.x, t = threadIdx.x;
    int v = (t < NBLK) ? bhist[t * NBUK + k] : 0;
    s[t] = v;
    __syncthreads();
#pragma unroll
    for (int o = 1; o < 512; o <<= 1) {
        int x = (t >= o) ? s[t - o] : 0;
        __syncthreads();
        s[t] += x;
        __syncthreads();
    }
    if (t < NBLK) base_excl[t * NBUK + k] = s[t] - v;
    if (t == 511) coltot[k] = s[511];
}

// ---- exclusive scan of bucket totals ----
__global__ __launch_bounds__(1024) void k_scanb2(const int* __restrict__ coltot,
                                                 int* __restrict__ bstart,
                                                 int* __restrict__ bcnt) {
    __shared__ int s[1024];
    int t = threadIdx.x;
    int v = (t < NBUK) ? coltot[t] : 0;
    s[t] = v;
    __syncthreads();
#pragma unroll
    for (int o = 1; o < 1024; o <<= 1) {
        int x = (t >= o) ? s[t - o] : 0;
        __syncthreads();
        s[t] += x;
        __syncthreads();
    }
    if (t < NBUK) { bstart[t] = s[t] - v; bcnt[t] = v; }
}

// ---- deterministic partition: ebuf[pos] = src | (dst&127)<<17 ----
__global__ __launch_bounds__(256) void k_scatter2(const int* __restrict__ ei,
                                                  const int* __restrict__ bstart,
                                                  const int* __restrict__ base_excl,
                                                  unsigned* __restrict__ ebuf) {
    __shared__ int cur[NBUK];
    int t = threadIdx.x, b = blockIdx.x;
    for (int i = t; i < NBUK; i += 256) cur[i] = 0;
    __syncthreads();
    int e0 = b * CHUNK;
    for (int r = 0; r < CHUNK; r += 256) {
        if (r + t < CHUNK) {
            int e = e0 + r + t;
            int sv = ei[e];
            int dv = ei[NE + e];
            int k = dv >> 7;
            int rk = atomicAdd(&cur[k], 1);   // LDS int atomic
            int pos = bstart[k] + base_excl[b * NBUK + k] + rk;
            ebuf[pos] = (unsigned)sv | ((unsigned)(dv & 127) << 17);
        }
    }
}

// ---- per-bucket counting sort -> dst-sorted csr, offsets/deg/dinv ----
__global__ __launch_bounds__(256) void k_sort(const int* __restrict__ bstart,
                                              const int* __restrict__ bcnt,
                                              const unsigned* __restrict__ ebuf,
                                              int* __restrict__ csr,
                                              int* __restrict__ offsets,
                                              int* __restrict__ deg,
                                              float* __restrict__ dinv) {
    __shared__ int hist[128];
    __shared__ int off[128];
    __shared__ int cur[128];
    int t = threadIdx.x, b = blockIdx.x;
    if (t < 128) hist[t] = 0;
    __syncthreads();
    int base = bstart[b], ne = bcnt[b];
    for (int i = t; i < ne; i += 256) atomicAdd(&hist[ebuf[base + i] >> 17], 1);
    __syncthreads();
    if (t < 128) off[t] = hist[t];
    __syncthreads();
#pragma unroll
    for (int o = 1; o < 128; o <<= 1) {
        int x = 0;
        if (t < 128 && t >= o) x = off[t - o];
        __syncthreads();
        if (t < 128) off[t] += x;
        __syncthreads();
    }
    if (t < 128) {
        int excl = off[t] - hist[t];
        cur[t] = excl;
        int node = b * 128 + t;
        if (node < NN) {
            offsets[node] = base + excl;   // absolute csr index
            deg[node]     = hist[t];
            dinv[node]    = rsqrtf((float)(hist[t] + 1));
        }
    }
    __syncthreads();
    for (int i = t; i < ne; i += 256) {
        unsigned pe = ebuf[base + i];
        int dl = pe >> 17;
        int pos = atomicAdd(&cur[dl], 1);  // LDS int atomic
        csr[base + pos] = (int)(pe & 0x1FFFF);
    }
}

// ---- MFMA GEMM 1: hp[n][d] = bf16( dinv[n] * sum_k x[n][k] W[k][d] ) ----
// block = 64 nodes, 4 waves; wave = 16 nodes x 64 cols, K=128
__global__ __launch_bounds__(256) void k_gemm1(const float* __restrict__ x,
                                               const float* __restrict__ Wf,
                                               const float* __restrict__ dinv,
                                               ushort_t* __restrict__ hp) {
    __shared__ __align__(16) ushort_t xs[64 * 136];   // x tile bf16, +8 pad
    __shared__ __align__(16) ushort_t wt[64 * 136];   // W^T bf16: wt[d][k]
    __shared__ float dv[64];
    int t = threadIdx.x;
    int node0 = blockIdx.x * 64;

    // stage W transposed (coalesced global read, once per block; L2-hit)
#pragma unroll 1
    for (int r = 0; r < 32; ++r) {
        int i = r * 256 + t;           // 8192 = 128k x 64d
        int k = i >> 6, d = i & 63;
        wt[d * 136 + k] = f2bf(Wf[i]);
    }
    // stage x tile as bf16 (float4 coalesced)
#pragma unroll 1
    for (int r = 0; r < 8; ++r) {
        int i4 = r * 256 + t;          // 2048 float4s
        int flat = i4 * 4;
        int nl = flat >> 7, k = flat & 127;
        int gn = node0 + nl; gn = gn < NN ? gn : NN - 1;
        float4 v = *(const float4*)(x + (size_t)gn * 128 + k);
        unsigned u0 = (unsigned)f2bf(v.x) | ((unsigned)f2bf(v.y) << 16);
        unsigned u1 = (unsigned)f2bf(v.z) | ((unsigned)f2bf(v.w) << 16);
        uint2 p; p.x = u0; p.y = u1;
        *(uint2*)&xs[nl * 136 + k] = p;
    }
    if (t < 64) { int gn = node0 + t; dv[t] = dinv[gn < NN ? gn : NN - 1]; }
    __syncthreads();

    int w = t >> 6, lane = t & 63;
    int l15 = lane & 15, quad = lane >> 4;
    f32x4 acc[4];
#pragma unroll
    for (int ct = 0; ct < 4; ++ct) { acc[ct][0]=0.f; acc[ct][1]=0.f; acc[ct][2]=0.f; acc[ct][3]=0.f; }

#pragma unroll
    for (int kt = 0; kt < 4; ++kt) {
        bf16x8 av = *(const bf16x8*)&xs[(w * 16 + l15) * 136 + kt * 32 + quad * 8];
#pragma unroll
        for (int ct = 0; ct < 4; ++ct) {
            bf16x8 bv = *(const bf16x8*)&wt[(ct * 16 + l15) * 136 + kt * 32 + quad * 8];
            acc[ct] = __builtin_amdgcn_mfma_f32_16x16x32_bf16(av, bv, acc[ct], 0, 0, 0);
        }
    }
    // C/D: col = l15, row = quad*4 + reg  [m89-verified]
#pragma unroll
    for (int reg = 0; reg < 4; ++reg) {
        int nl = w * 16 + quad * 4 + reg;
        int gn = node0 + nl;
        if (gn < NN) {
            float dvv = dv[nl];
#pragma unroll
            for (int ct = 0; ct < 4; ++ct)
                hp[(size_t)gn * 64 + ct * 16 + l15] = f2bf(dvv * acc[ct][reg]);
        }
    }
}

// ---- gather-side aggregation: one wave per node, register accumulation ----
__global__ __launch_bounds__(256) void k_gather(const int* __restrict__ offsets,
                                                const int* __restrict__ deg,
                                                const int* __restrict__ csr,
                                                const float* __restrict__ dinv,
                                                const ushort_t* __restrict__ hp,
                                                const float* __restrict__ b_conv,
                                                ushort_t* __restrict__ a) {
    int node = (blockIdx.x * 256 + threadIdx.x) >> 6;   // grid exactly NN waves
    int lane = threadIdx.x & 63;
    int start = offsets[node];
    int cnt   = deg[node];

    float s0 = 0.f, s1 = 0.f, s2 = 0.f, s3 = 0.f;
#pragma unroll 1
    for (int j0 = 0; j0 < cnt; j0 += 64) {
        int m = cnt - j0; m = m < 64 ? m : 64;   // wave-uniform
        int col = 0;
        if (lane < m) col = csr[start + j0 + lane];
        int jj = 0;
#pragma unroll 1
        for (; jj + 8 <= m; jj += 8) {
            int c[8];
#pragma unroll
            for (int u = 0; u < 8; ++u) c[u] = __shfl(col, jj + u, 64);
            float v[8];
#pragma unroll
            for (int u = 0; u < 8; ++u) v[u] = bf2f(hp[(size_t)c[u] * 64 + lane]);
            s0 += v[0] + v[4]; s1 += v[1] + v[5]; s2 += v[2] + v[6]; s3 += v[3] + v[7];
        }
        for (; jj < m; ++jj) {
            int c = __shfl(col, jj, 64);
            s0 += bf2f(hp[(size_t)c * 64 + lane]);
        }
    }
    float acc = (s0 + s1) + (s2 + s3);
    acc += bf2f(hp[(size_t)node * 64 + lane]);          // self-loop
    float v = dinv[node] * acc + b_conv[lane];
    a[(size_t)node * 64 + lane] = f2bf(fmaxf(v, 0.f));
}

// ---- MFMA epilogue GEMM: out[n][j] = sum_k a[n][k] W2[k][j] + b_lin[j] ----
// block = 64 nodes, 4 waves; wave = 16 nodes x 128 cols, K=64
__global__ __launch_bounds__(256) void k_epi(const ushort_t* __restrict__ a,
                                             const float* __restrict__ W2f,
                                             const float* __restrict__ blin,
                                             float* __restrict__ out) {
    __shared__ __align__(16) ushort_t as[64 * 72];     // a tile bf16, +8 pad
    __shared__ __align__(16) ushort_t w2t[128 * 72];   // W2^T bf16: w2t[j][k]
    __shared__ float bl[128];
    int t = threadIdx.x;
    int node0 = blockIdx.x * 64;

    // stage a tile (uint4 coalesced)
#pragma unroll
    for (int r = 0; r < 2; ++r) {
        int i8 = r * 256 + t;          // 512 chunks of 8 bf16
        int flat = i8 * 8;
        int nl = flat >> 6, k = flat & 63;
        int gn = node0 + nl; gn = gn < NN ? gn : NN - 1;
        uint4 v = *(const uint4*)(a + (size_t)gn * 64 + k);
        *(uint4*)&as[nl * 72 + k] = v;
    }
    // stage W2 transposed
#pragma unroll 1
    for (int r = 0; r < 32; ++r) {
        int i = r * 256 + t;           // 8192 = 64k x 128j
        int k = i >> 7, j = i & 127;
        w2t[j * 72 + k] = f2bf(W2f[i]);
    }
    if (t < 128) bl[t] = blin[t];
    __syncthreads();

    int w = t >> 6, lane = t & 63;
    int l15 = lane & 15, quad = lane >> 4;
    f32x4 acc[8];
#pragma unroll
    for (int ct = 0; ct < 8; ++ct) { acc[ct][0]=0.f; acc[ct][1]=0.f; acc[ct][2]=0.f; acc[ct][3]=0.f; }

#pragma unroll
    for (int kt = 0; kt < 2; ++kt) {
        bf16x8 av = *(const bf16x8*)&as[(w * 16 + l15) * 72 + kt * 32 + quad * 8];
#pragma unroll
        for (int ct = 0; ct < 8; ++ct) {
            bf16x8 bv = *(const bf16x8*)&w2t[(ct * 16 + l15) * 72 + kt * 32 + quad * 8];
            acc[ct] = __builtin_amdgcn_mfma_f32_16x16x32_bf16(av, bv, acc[ct], 0, 0, 0);
        }
    }
#pragma unroll
    for (int reg = 0; reg < 4; ++reg) {
        int nl = w * 16 + quad * 4 + reg;
        int gn = node0 + nl;
        if (gn < NN) {
#pragma unroll
            for (int ct = 0; ct < 8; ++ct) {
                int j = ct * 16 + l15;
                out[(size_t)gn * 128 + j] = acc[ct][reg] + bl[j];
            }
        }
    }
}

extern "C" void kernel_launch(void* const* d_in, const int* in_sizes, int n_in,
                              void* d_out, int out_size, void* d_ws, size_t ws_size,
                              hipStream_t stream) {
    const float* x  = (const float*)d_in[0];
    const int*   ei = (const int*)d_in[1];
    const float* Wc = (const float*)d_in[2];
    const float* bc = (const float*)d_in[3];
    const float* Wl = (const float*)d_in[4];
    const float* bl = (const float*)d_in[5];
    float* out = (float*)d_out;

    char* ws = (char*)d_ws;
    // total 42.1 MB; every byte written before read -> no memset needed
    int*      bhist     = (int*)(ws + 0);              // 1251200
    int*      base_excl = (int*)(ws + 1251200);        // 1251200
    int*      coltot    = (int*)(ws + 2502400);        // 3200
    int*      bstart    = (int*)(ws + 2505600);        // 3200
    int*      bcnt      = (int*)(ws + 2508800);        // 3200
    int*      offsets   = (int*)(ws + 2512000);        // 400384
    int*      deg       = (int*)(ws + 2912384);        // 400384
    float*    dinv      = (float*)(ws + 3312768);      // 400384
    unsigned* ebuf      = (unsigned*)(ws + 3713152);   // 6400000
    int*      csr       = (int*)(ws + 10113152);       // 6400000
    ushort_t* hp        = (ushort_t*)(ws + 16513152);  // 12800000 (bf16)
    ushort_t* a         = (ushort_t*)(ws + 29313152);  // 12800000 (bf16)

    k_part_hist<<<NBLK, 256, 0, stream>>>(ei + NE, bhist);
    k_colscan <<<NBUK, 512, 0, stream>>>(bhist, base_excl, coltot);
    k_scanb2  <<<1, 1024, 0, stream>>>(coltot, bstart, bcnt);
    k_scatter2<<<NBLK, 256, 0, stream>>>(ei, bstart, base_excl, ebuf);
    k_sort    <<<NBUK, 256, 0, stream>>>(bstart, bcnt, ebuf, csr, offsets, deg, dinv);
    k_gemm1   <<<NGB, 256, 0, stream>>>(x, Wc, dinv, hp);
    k_gather  <<<NN * 64 / 256, 256, 0, stream>>>(offsets, deg, csr, dinv, hp, bc, a);
    k_epi     <<<NGB, 256, 0, stream>>>(a, Wl, bl, out);
}